// Round 5
// baseline (588.932 us; speedup 1.0000x reference)
//
#include <hip/hip_runtime.h>

// ROI Align (max) — R8: one block per box, synchronized channel sweep.
//
// R7 post-mortem: FETCH 634 MB / WRITE 638 MB — 1500+ co-resident blocks
// spanned all 8 cg-octets -> concurrent read set ~124 MB >> L2 -> thrash;
// thrash evicted partial dirty store lines -> 25x write amplification.
// The pipelined loop itself was perfect (VALU 2.9%).
//
// R8: grid = 512 (one block per box), 512 threads, CG=8 channels/tile,
// 32 tiles swept in the SAME order by all blocks. All blocks co-resident
// (2/CU, LDS 2x53.9 KB); concurrent working set = one 8-channel cohort
// (~2 MB/XCD incl. 8x box overlap). Drift is self-pacing: racing ahead ->
// HBM miss (slow down); lagging -> L2 hit (catch up). Blocks live the whole
// kernel: prefetch pipeline (R4/R7's proven loop) hides latency, fixed
// per-box work amortizes 32x. Stores: 1568 B/iter, contiguous line-aligned
// 50176 B per block -> no write amplification.
//
// feature: (2, 256, 200, 304) fp32; boxes: (512,4); batch_idx: (512,) i32
// out: (512, 256, 7, 7) fp32. SPATIAL_SCALE=0.25, POOLED=7, SR=2, MODE=max.

#define SPATIAL_SCALE 0.25f
#define POOLED 7
#define SR 2

constexpr int Cc = 256;
constexpr int Hc = 200;
constexpr int Wc = 304;
constexpr int Nc = 512;

constexpr int CG      = 8;               // channels per tile (one per wave)
constexpr int TILES   = Cc / CG;         // 32 tile iterations per block
constexpr int NSAMP   = POOLED * SR;     // 14 sample coords per axis
constexpr int NROW    = NSAMP * 2;       // 28 row slots (y0 0..13, y1 14..27)
constexpr int XPAD    = 60;              // LDS row stride (writes <= 56 cols)
constexpr int CH_STR  = NROW * XPAD;     // 1680 floats per channel
constexpr int CELLS   = POOLED * POOLED; // 49
constexpr int OUTS    = CG * CELLS;      // 392 outputs per tile
constexpr int PER_BOX = Cc * CELLS;      // 12544
constexpr int PLANE   = Hc * Wc;         // 60800
constexpr int A1_OFF  = NSAMP * XPAD;    // y1 block offset within channel

__global__ __launch_bounds__(512) void roi_align_max_kernel(
    const float* __restrict__ feature,
    const float* __restrict__ boxes,
    const int*   __restrict__ batch_idx,
    float*       __restrict__ out)
{
    __shared__ float lds[CG * CH_STR];   // 53,760 B -> 2 blocks/CU
    __shared__ int   rowoff_sh[NROW];

    const int n   = blockIdx.x;          // box; XCD = n % 8
    const int tid = threadIdx.x;

    // ---- box math (block-uniform -> scalar) ----
    const float rsx = boxes[n * 4 + 0] * SPATIAL_SCALE;
    const float rsy = boxes[n * 4 + 1] * SPATIAL_SCALE;
    const float rex = boxes[n * 4 + 2] * SPATIAL_SCALE;
    const float rey = boxes[n * 4 + 3] * SPATIAL_SCALE;
    const float roi_w = fmaxf(rex - rsx, 1.0f);
    const float roi_h = fmaxf(rey - rsy, 1.0f);
    const float bin_w = roi_w / (float)POOLED;
    const float bin_h = roi_h / (float)POOLED;
    const int   b     = batch_idx[n];

    const float x_first = __fadd_rn(rsx, __fmul_rn(0.25f, bin_w));
    const float xc0     = fminf(fmaxf(x_first, 0.0f), (float)(Wc - 1));
    const int   xbase   = ((int)floorf(xc0)) & ~3;

    // dynamic span: last x sample (px = 6.75) is the monotone max.
    const float x_last = __fadd_rn(rsx, __fmul_rn(6.75f, bin_w));
    const float xlc    = fminf(fmaxf(x_last, 0.0f), (float)(Wc - 1));
    const int   x0l    = (int)floorf(xlc);
    const int   xlastc = min(x0l + 1, Wc - 1);
    const int   span   = xlastc - xbase + 1;      // <= 54
    const int   nl4    = (span + 4) >> 2;         // +guard; <= 14 float4 lanes

    // ---- cooperative row offsets (28 threads) ----
    if (tid < NROW) {
        const int  which = tid >= NSAMP;
        const int  s     = which ? tid - NSAMP : tid;
        const float py   = fmaf((float)s, 0.5f, 0.25f);   // p + (sub+.5)/2 exact
        const float fy   = __fadd_rn(rsy, __fmul_rn(py, bin_h));
        const float fyc  = fminf(fmaxf(fy, 0.0f), (float)(Hc - 1));
        const int   y0   = (int)floorf(fyc);
        const int   row  = which ? min(y0 + 1, Hc - 1) : y0;
        rowoff_sh[tid] = row * Wc;
    }
    __syncthreads();

    // ---- staging setup + first tile's loads (issued ASAP) ----
    const int c_st   = tid >> 6;         // wave = channel within tile (0..7)
    const int lane16 = tid & 15;
    const int rquad  = (tid >> 4) & 3;
    const int col    = min(xbase + lane16 * 4, Wc - 4);
    const bool act   = (lane16 < nl4);

    int ro[7];
    #pragma unroll
    for (int it = 0; it < 7; ++it)
        ro[it] = rowoff_sh[it * 4 + rquad];        // broadcast reads

    const float* __restrict__ gp =
        feature + ((size_t)b * Cc + c_st) * (size_t)PLANE;
    float4 st[7];
    if (act) {
        #pragma unroll
        for (int it = 0; it < 7; ++it)
            st[it] = *(const float4*)(gp + ro[it] + col);
    }
    const int lw = c_st * CH_STR + rquad * XPAD + lane16 * 4;

    // ---- per-thread compute metadata (overlaps first loads' latency) ----
    const int cellc = min(tid, OUTS - 1);
    const int c_cl  = cellc / CELLS;
    const int cell  = cellc - c_cl * CELLS;
    const int ph    = cell / POOLED;
    const int pw    = cell - ph * POOLED;

    float w00[2][2], w01[2][2], w10[2][2], w11[2][2];
    int   a0t[2][2];                     // absolute LDS float index of y0 tap
    #pragma unroll
    for (int sy = 0; sy < SR; ++sy) {
        const int   sY  = ph * SR + sy;
        const float py  = (float)ph + ((float)sy + 0.5f) * 0.5f;
        const float fy  = __fadd_rn(rsy, __fmul_rn(py, bin_h));
        const bool  vy  = (fy > -1.0f) && (fy < (float)Hc);
        const float fyc = fminf(fmaxf(fy, 0.0f), (float)(Hc - 1));
        const int   y0i = (int)floorf(fyc);
        const float ly  = fyc - (float)y0i;
        const float hy  = 1.0f - ly;
        #pragma unroll
        for (int sx = 0; sx < SR; ++sx) {
            const float px  = (float)pw + ((float)sx + 0.5f) * 0.5f;
            const float fx  = __fadd_rn(rsx, __fmul_rn(px, bin_w));
            const bool  vx  = (fx > -1.0f) && (fx < (float)Wc);
            const float fxc = fminf(fmaxf(fx, 0.0f), (float)(Wc - 1));
            const int   x0i = (int)floorf(fxc);
            const float lx  = fxc - (float)x0i;
            const float hx  = 1.0f - lx;
            const int   c0  = x0i - xbase;
            const bool  v   = vy && vx;      // validity folded into weights
            w00[sy][sx] = v ? hy * hx : 0.0f;
            w01[sy][sx] = v ? hy * lx : 0.0f;
            w10[sy][sx] = v ? ly * hx : 0.0f;
            w11[sy][sx] = v ? ly * lx : 0.0f;
            a0t[sy][sx] = c_cl * CH_STR + sY * XPAD + c0;
        }
    }
    float* __restrict__ outp = out + (size_t)n * PER_BOX
                             + (size_t)c_cl * CELLS + cell;

    // ---- pipelined tile loop: ds_write j, prefetch j+1, compute j ----
    for (int j = 0; j < TILES; ++j) {
        if (act) {
            #pragma unroll
            for (int it = 0; it < 7; ++it)
                *(float4*)&lds[lw + it * (4 * XPAD)] = st[it];
            if (j + 1 < TILES) {
                gp += (size_t)CG * PLANE;           // next 8 channels
                #pragma unroll
                for (int it = 0; it < 7; ++it)
                    st[it] = *(const float4*)(gp + ro[it] + col);
            }
        }
        __syncthreads();                 // staging visible

        if (tid < OUTS) {
            float m = -INFINITY;
            #pragma unroll
            for (int sy = 0; sy < SR; ++sy) {
                #pragma unroll
                for (int sx = 0; sx < SR; ++sx) {
                    const int a0 = a0t[sy][sx];
                    const float bil = w00[sy][sx] * lds[a0]
                                    + w01[sy][sx] * lds[a0 + 1]
                                    + w10[sy][sx] * lds[a0 + A1_OFF]
                                    + w11[sy][sx] * lds[a0 + A1_OFF + 1];
                    m = fmaxf(m, bil);
                }
            }
            *outp = m;                   // plain store
            outp += OUTS;                // next tile's channel chunk
        }
        __syncthreads();                 // LDS reads done before next writes
    }
}

extern "C" void kernel_launch(void* const* d_in, const int* in_sizes, int n_in,
                              void* d_out, int out_size, void* d_ws, size_t ws_size,
                              hipStream_t stream) {
    const float* feature   = (const float*)d_in[0];
    const float* boxes     = (const float*)d_in[1];
    const int*   batch_idx = (const int*)d_in[2];
    float*       out       = (float*)d_out;

    roi_align_max_kernel<<<Nc, 512, 0, stream>>>(feature, boxes,
                                                 batch_idx, out);
}

// Round 6
// 227.054 us; speedup vs baseline: 2.5938x; 2.5938x over previous
//
#include <hip/hip_runtime.h>

// ROI Align (max) — R9: async global->LDS pipeline, barrier-free waves.
//
// R8 post-mortem: WRITE 680 MB ~= FETCH 645 MB, a ~26x symmetric blowup seen
// ONLY in the register-staged multi-tile kernels (R4/R7/R8) and never in
// one-shot kernels with the identical store pattern -> scratch spill/fill of
// the float4 st[7] staging state (VGPR_Count 40-44 << ~55 live values).
// Spill traffic thrashed L2, which also destroyed cohort locality + pacing.
//
// R9: no staging registers at all. __builtin_amdgcn_global_load_lds (16B,
// direct HBM->LDS DMA) into a double-buffered LDS tile; explicit counted
// s_waitcnt vmcnt(7) (T4: never drain to 0 in the loop). Each wave stages
// AND computes its own channel -> zero __syncthreads (no barrier vmcnt(0)
// drain, no cross-wave deps). Grid=512 (block=box, all 512 co-resident at
// 2 blocks/CU), 4 waves = 4 channels/tile, 64 tiles swept in the same order
// by every block: concurrent read set = ~1 cohort; depth-1 prefetch is
// self-pacing (leader stalls on HBM miss at vmcnt, laggard L2-hits).
//
// LDS layout per channel: 7 groups x (4 row-slots x 64 floats) + 8-float
// group pad (GRP=264) -> gll's lane-linear 1024B writes land exactly on one
// group; slot bank bases spread {0,8,16,24}. Slots: y0 rows 0..13, y1 14..27.
//
// feature: (2, 256, 200, 304) fp32; boxes: (512,4); batch_idx: (512,) i32
// out: (512, 256, 7, 7) fp32. SPATIAL_SCALE=0.25, POOLED=7, SR=2, MODE=max.

#define SPATIAL_SCALE 0.25f
#define POOLED 7
#define SR 2

constexpr int Cc = 256;
constexpr int Hc = 200;
constexpr int Wc = 304;
constexpr int Nc = 512;

constexpr int CG      = 4;               // channels per tile = waves per block
constexpr int TILES   = Cc / CG;         // 64 tile iterations
constexpr int NSAMP   = POOLED * SR;     // 14 sample coords per axis
constexpr int NROW    = NSAMP * 2;       // 28 row slots (y0 0..13, y1 14..27)
constexpr int GRP     = 264;             // floats per 4-slot group (1024B+32B pad)
constexpr int CH_F    = 7 * GRP;         // 1848 floats per channel per buffer
constexpr int BUF_F   = CG * CH_F;       // 7392 floats per buffer
constexpr int CELLS   = POOLED * POOLED; // 49
constexpr int PER_BOX = Cc * CELLS;      // 12544
constexpr int PLANE   = Hc * Wc;         // 60800

__global__ __launch_bounds__(256) void roi_align_max_kernel(
    const float* __restrict__ feature,
    const float* __restrict__ boxes,
    const int*   __restrict__ batch_idx,
    float*       __restrict__ out)
{
    __shared__ float lds[2 * BUF_F];     // 59,136 B -> 2 blocks/CU (512 resident)

    const int n   = blockIdx.x;          // box; XCD = n % 8
    const int tid = threadIdx.x;
    const int wv     = tid >> 6;         // wave = channel within tile
    const int lane   = tid & 63;
    const int lane16 = lane & 15;
    const int rquad  = lane >> 4;

    // ---- box math (block-uniform -> scalar) ----
    const float rsx = boxes[n * 4 + 0] * SPATIAL_SCALE;
    const float rsy = boxes[n * 4 + 1] * SPATIAL_SCALE;
    const float rex = boxes[n * 4 + 2] * SPATIAL_SCALE;
    const float rey = boxes[n * 4 + 3] * SPATIAL_SCALE;
    const float roi_w = fmaxf(rex - rsx, 1.0f);
    const float roi_h = fmaxf(rey - rsy, 1.0f);
    const float bin_w = roi_w / (float)POOLED;
    const float bin_h = roi_h / (float)POOLED;
    const int   b     = batch_idx[n];

    const float x_first = __fadd_rn(rsx, __fmul_rn(0.25f, bin_w));
    const float xc0     = fminf(fmaxf(x_first, 0.0f), (float)(Wc - 1));
    const int   xbase   = ((int)floorf(xc0)) & ~3;

    const float x_last = __fadd_rn(rsx, __fmul_rn(6.75f, bin_w));
    const float xlc    = fminf(fmaxf(x_last, 0.0f), (float)(Wc - 1));
    const int   x0l    = (int)floorf(xlc);
    const int   xlastc = min(x0l + 1, Wc - 1);
    const int   span   = xlastc - xbase + 1;      // <= 54
    const int   nl4    = (span + 4) >> 2;         // +guard; <= 14 float4 lanes

    // ---- per-lane staging rows: lane (rquad,lane16) covers slots it*4+rquad ----
    int ro[7];
    #pragma unroll
    for (int it = 0; it < 7; ++it) {
        const int  slot  = it * 4 + rquad;
        const int  which = slot >= NSAMP;
        const int  sY    = which ? slot - NSAMP : slot;
        const float py   = fmaf((float)sY, 0.5f, 0.25f);
        const float fy   = __fadd_rn(rsy, __fmul_rn(py, bin_h));
        const float fyc  = fminf(fmaxf(fy, 0.0f), (float)(Hc - 1));
        const int   y0   = (int)floorf(fyc);
        const int   row  = which ? min(y0 + 1, Hc - 1) : y0;
        ro[it] = row * Wc;
    }
    const int  col = min(xbase + lane16 * 4, Wc - 4);  // clamped cols never read
    const bool act = (lane16 < nl4);

    // ---- compute metadata: this wave's channel, cell = lane (49 lanes) ----
    const int cell = min(lane, CELLS - 1);
    const int ph   = cell / POOLED;
    const int pw   = cell - ph * POOLED;

    float w00[2][2], w01[2][2], w10[2][2], w11[2][2];
    int   r0a[2][2], r1a[2][2];          // buffer-relative float offsets
    #pragma unroll
    for (int sy = 0; sy < SR; ++sy) {
        const int   sY  = ph * SR + sy;
        const float py  = (float)ph + ((float)sy + 0.5f) * 0.5f;
        const float fy  = __fadd_rn(rsy, __fmul_rn(py, bin_h));
        const bool  vy  = (fy > -1.0f) && (fy < (float)Hc);
        const float fyc = fminf(fmaxf(fy, 0.0f), (float)(Hc - 1));
        const int   y0i = (int)floorf(fyc);
        const float ly  = fyc - (float)y0i;
        const float hy  = 1.0f - ly;
        #pragma unroll
        for (int sx = 0; sx < SR; ++sx) {
            const float px  = (float)pw + ((float)sx + 0.5f) * 0.5f;
            const float fx  = __fadd_rn(rsx, __fmul_rn(px, bin_w));
            const bool  vx  = (fx > -1.0f) && (fx < (float)Wc);
            const float fxc = fminf(fmaxf(fx, 0.0f), (float)(Wc - 1));
            const int   x0i = (int)floorf(fxc);
            const float lx  = fxc - (float)x0i;
            const float hx  = 1.0f - lx;
            const int   c0  = x0i - xbase;
            const bool  v   = vy && vx;      // validity folded into weights
            w00[sy][sx] = v ? hy * hx : 0.0f;
            w01[sy][sx] = v ? hy * lx : 0.0f;
            w10[sy][sx] = v ? ly * hx : 0.0f;
            w11[sy][sx] = v ? ly * lx : 0.0f;
            const int s0 = sY;               // y0 slot
            const int s1 = NSAMP + sY;       // y1 slot
            r0a[sy][sx] = (s0 >> 2) * GRP + (s0 & 3) * 64 + c0;
            r1a[sy][sx] = (s1 >> 2) * GRP + (s1 & 3) * 64 + c0;
        }
    }

    // ---- async staging: tile t channel = t*CG + wv ----
    const float* __restrict__ gp0 =
        feature + ((size_t)b * Cc + wv) * (size_t)PLANE;

#define ISSUE_TILE(GT, Q)                                                     \
    if (act) {                                                                \
        _Pragma("unroll")                                                     \
        for (int it = 0; it < 7; ++it) {                                      \
            const float* gsrc = (GT) + ro[it] + col;                          \
            const int lofs = __builtin_amdgcn_readfirstlane(                  \
                ((Q) * BUF_F + wv * CH_F + it * GRP) * 4);                    \
            __builtin_amdgcn_global_load_lds(                                 \
                (const __attribute__((address_space(1))) unsigned int*)       \
                    (const void*)gsrc,                                        \
                (__attribute__((address_space(3))) unsigned int*)             \
                    (void*)((char*)lds + lofs),                               \
                16, 0, 0);                                                    \
        }                                                                     \
    }

    // prologue: tile 0 -> buffer 0
    ISSUE_TILE(gp0, 0)
    const float* __restrict__ gnext = gp0 + (size_t)CG * PLANE;

    for (int j = 0; j < TILES; ++j) {
        if (j + 1 < TILES) {
            ISSUE_TILE(gnext, ((j + 1) & 1))
            gnext += (size_t)CG * PLANE;
            // wait until only tile j+1's 7 loads remain -> tile j complete
            asm volatile("s_waitcnt vmcnt(7)" ::: "memory");
        } else {
            asm volatile("s_waitcnt vmcnt(0)" ::: "memory");
        }

        const int qb = (j & 1) * BUF_F + wv * CH_F;
        float m = -INFINITY;
        #pragma unroll
        for (int sy = 0; sy < SR; ++sy) {
            #pragma unroll
            for (int sx = 0; sx < SR; ++sx) {
                const int a0 = qb + r0a[sy][sx];
                const int a1 = qb + r1a[sy][sx];
                const float bil = w00[sy][sx] * lds[a0]
                                + w01[sy][sx] * lds[a0 + 1]
                                + w10[sy][sx] * lds[a1]
                                + w11[sy][sx] * lds[a1 + 1];
                m = fmaxf(m, bil);
            }
        }
        if (lane < CELLS)
            out[(size_t)n * PER_BOX + (size_t)(j * CG + wv) * CELLS + cell] = m;
    }
#undef ISSUE_TILE
}

extern "C" void kernel_launch(void* const* d_in, const int* in_sizes, int n_in,
                              void* d_out, int out_size, void* d_ws, size_t ws_size,
                              hipStream_t stream) {
    const float* feature   = (const float*)d_in[0];
    const float* boxes     = (const float*)d_in[1];
    const int*   batch_idx = (const int*)d_in[2];
    float*       out       = (float*)d_out;

    roi_align_max_kernel<<<Nc, 256, 0, stream>>>(feature, boxes,
                                                 batch_idx, out);
}

// Round 7
// 223.544 us; speedup vs baseline: 2.6345x; 1.0157x over previous
//
#include <hip/hip_runtime.h>

// ROI Align (max) — R10: R9 + spatial box->XCD clustering.
//
// R9 post-mortem: WRITE fixed (25.7 MB), dur 92.6 us best, but VALU 8.6% /
// HBM 39% / occ 18% -> nothing saturated. Arithmetic: FETCH 255 MB = 2.4x
// feature because each XCD's 64 RANDOM boxes cover ~61% of BOTH batches'
// plane lines, fetched as scattered 128-256B segments (random-line HBM
// sustains ~3.5 TB/s, not 6.3) -> 255MB/3.5 ~= 85 us = the measured floor.
// Bottleneck = redundant, poorly-localized HBM fetch.
//
// R10: tiny rank kernel buckets boxes by key = batch*4 + y-band(cy) and
// writes a bijective perm (rank = popcount(ballot(key_j < key_n || tie)));
// main kernel (R9 verbatim otherwise) takes n = perm[(bid%8)*64 + bid/8],
// so XCD x's 64 boxes share one batch + one ~50-row band (+-26 spill)
// ~= 51% of ONE batch vs 61% of BOTH -> ~2.3x less fetch, y-banded
// (sequential-ish) HBM access. Bucket imbalance spills into the adjacent
// band of the same batch only.
//
// feature: (2, 256, 200, 304) fp32; boxes: (512,4); batch_idx: (512,) i32
// out: (512, 256, 7, 7) fp32. SPATIAL_SCALE=0.25, POOLED=7, SR=2, MODE=max.

#define SPATIAL_SCALE 0.25f
#define POOLED 7
#define SR 2

constexpr int Cc = 256;
constexpr int Hc = 200;
constexpr int Wc = 304;
constexpr int Nc = 512;

constexpr int CG      = 4;               // channels per tile = waves per block
constexpr int TILES   = Cc / CG;         // 64 tile iterations
constexpr int NSAMP   = POOLED * SR;     // 14 sample coords per axis
constexpr int NROW    = NSAMP * 2;       // 28 row slots (y0 0..13, y1 14..27)
constexpr int GRP     = 264;             // floats per 4-slot group (1024B+32B pad)
constexpr int CH_F    = 7 * GRP;         // 1848 floats per channel per buffer
constexpr int BUF_F   = CG * CH_F;       // 7392 floats per buffer
constexpr int CELLS   = POOLED * POOLED; // 49
constexpr int PER_BOX = Cc * CELLS;      // 12544
constexpr int PLANE   = Hc * Wc;         // 60800

// ====================== box spatial-rank kernel ======================
// Bijective perm: boxes sorted by (batch, y-band, index). One wave per box.
__global__ __launch_bounds__(64) void box_rank_kernel(
    const float* __restrict__ boxes,
    const int*   __restrict__ batch_idx,
    int*         __restrict__ perm)
{
    const int n = blockIdx.x;
    const int l = threadIdx.x;

    const float cyn  = (boxes[n * 4 + 1] + boxes[n * 4 + 3])
                     * (0.5f * SPATIAL_SCALE);
    const int  bandn = min(3, max(0, (int)(cyn * (4.0f / (float)Hc))));
    const int  keyn  = batch_idx[n] * 4 + bandn;

    int rank = 0;
    #pragma unroll
    for (int m = 0; m < Nc / 64; ++m) {
        const int j = m * 64 + l;
        const float cyj  = (boxes[j * 4 + 1] + boxes[j * 4 + 3])
                         * (0.5f * SPATIAL_SCALE);
        const int  bandj = min(3, max(0, (int)(cyj * (4.0f / (float)Hc))));
        const int  keyj  = batch_idx[j] * 4 + bandj;
        const bool lt = (keyj < keyn) || (keyj == keyn && j < n);
        rank += (int)__popcll(__ballot(lt));   // uniform across lanes
    }
    if (l == 0) perm[rank] = n;
}

// ============================== main =================================
template <bool USE_PERM>
__global__ __launch_bounds__(256) void roi_align_max_kernel(
    const float* __restrict__ feature,
    const float* __restrict__ boxes,
    const int*   __restrict__ batch_idx,
    const int*   __restrict__ perm,
    float*       __restrict__ out)
{
    __shared__ float lds[2 * BUF_F];     // 59,136 B -> 2 blocks/CU

    const int bid = blockIdx.x;
    // XCD = bid % 8 (round-robin dispatch); rank-block x -> XCD x.
    const int n = USE_PERM ? perm[(bid & 7) * 64 + (bid >> 3)] : bid;
    const int tid = threadIdx.x;
    const int wv     = tid >> 6;         // wave = channel within tile
    const int lane   = tid & 63;
    const int lane16 = lane & 15;
    const int rquad  = lane >> 4;

    // ---- box math (block-uniform -> scalar) ----
    const float rsx = boxes[n * 4 + 0] * SPATIAL_SCALE;
    const float rsy = boxes[n * 4 + 1] * SPATIAL_SCALE;
    const float rex = boxes[n * 4 + 2] * SPATIAL_SCALE;
    const float rey = boxes[n * 4 + 3] * SPATIAL_SCALE;
    const float roi_w = fmaxf(rex - rsx, 1.0f);
    const float roi_h = fmaxf(rey - rsy, 1.0f);
    const float bin_w = roi_w / (float)POOLED;
    const float bin_h = roi_h / (float)POOLED;
    const int   b     = batch_idx[n];

    const float x_first = __fadd_rn(rsx, __fmul_rn(0.25f, bin_w));
    const float xc0     = fminf(fmaxf(x_first, 0.0f), (float)(Wc - 1));
    const int   xbase   = ((int)floorf(xc0)) & ~3;

    const float x_last = __fadd_rn(rsx, __fmul_rn(6.75f, bin_w));
    const float xlc    = fminf(fmaxf(x_last, 0.0f), (float)(Wc - 1));
    const int   x0l    = (int)floorf(xlc);
    const int   xlastc = min(x0l + 1, Wc - 1);
    const int   span   = xlastc - xbase + 1;      // <= 54
    const int   nl4    = (span + 4) >> 2;         // +guard; <= 14 float4 lanes

    // ---- per-lane staging rows: lane (rquad,lane16) covers slots it*4+rquad ----
    int ro[7];
    #pragma unroll
    for (int it = 0; it < 7; ++it) {
        const int  slot  = it * 4 + rquad;
        const int  which = slot >= NSAMP;
        const int  sY    = which ? slot - NSAMP : slot;
        const float py   = fmaf((float)sY, 0.5f, 0.25f);
        const float fy   = __fadd_rn(rsy, __fmul_rn(py, bin_h));
        const float fyc  = fminf(fmaxf(fy, 0.0f), (float)(Hc - 1));
        const int   y0   = (int)floorf(fyc);
        const int   row  = which ? min(y0 + 1, Hc - 1) : y0;
        ro[it] = row * Wc;
    }
    const int  col = min(xbase + lane16 * 4, Wc - 4);  // clamped cols never read
    const bool act = (lane16 < nl4);

    // ---- compute metadata: this wave's channel, cell = lane (49 lanes) ----
    const int cell = min(lane, CELLS - 1);
    const int ph   = cell / POOLED;
    const int pw   = cell - ph * POOLED;

    float w00[2][2], w01[2][2], w10[2][2], w11[2][2];
    int   r0a[2][2], r1a[2][2];          // buffer-relative float offsets
    #pragma unroll
    for (int sy = 0; sy < SR; ++sy) {
        const int   sY  = ph * SR + sy;
        const float py  = (float)ph + ((float)sy + 0.5f) * 0.5f;
        const float fy  = __fadd_rn(rsy, __fmul_rn(py, bin_h));
        const bool  vy  = (fy > -1.0f) && (fy < (float)Hc);
        const float fyc = fminf(fmaxf(fy, 0.0f), (float)(Hc - 1));
        const int   y0i = (int)floorf(fyc);
        const float ly  = fyc - (float)y0i;
        const float hy  = 1.0f - ly;
        #pragma unroll
        for (int sx = 0; sx < SR; ++sx) {
            const float px  = (float)pw + ((float)sx + 0.5f) * 0.5f;
            const float fx  = __fadd_rn(rsx, __fmul_rn(px, bin_w));
            const bool  vx  = (fx > -1.0f) && (fx < (float)Wc);
            const float fxc = fminf(fmaxf(fx, 0.0f), (float)(Wc - 1));
            const int   x0i = (int)floorf(fxc);
            const float lx  = fxc - (float)x0i;
            const float hx  = 1.0f - lx;
            const int   c0  = x0i - xbase;
            const bool  v   = vy && vx;      // validity folded into weights
            w00[sy][sx] = v ? hy * hx : 0.0f;
            w01[sy][sx] = v ? hy * lx : 0.0f;
            w10[sy][sx] = v ? ly * hx : 0.0f;
            w11[sy][sx] = v ? ly * lx : 0.0f;
            const int s0 = sY;               // y0 slot
            const int s1 = NSAMP + sY;       // y1 slot
            r0a[sy][sx] = (s0 >> 2) * GRP + (s0 & 3) * 64 + c0;
            r1a[sy][sx] = (s1 >> 2) * GRP + (s1 & 3) * 64 + c0;
        }
    }

    // ---- async staging: tile t channel = t*CG + wv ----
    const float* __restrict__ gp0 =
        feature + ((size_t)b * Cc + wv) * (size_t)PLANE;

#define ISSUE_TILE(GT, Q)                                                     \
    if (act) {                                                                \
        _Pragma("unroll")                                                     \
        for (int it = 0; it < 7; ++it) {                                      \
            const float* gsrc = (GT) + ro[it] + col;                          \
            const int lofs = __builtin_amdgcn_readfirstlane(                  \
                ((Q) * BUF_F + wv * CH_F + it * GRP) * 4);                    \
            __builtin_amdgcn_global_load_lds(                                 \
                (const __attribute__((address_space(1))) unsigned int*)       \
                    (const void*)gsrc,                                        \
                (__attribute__((address_space(3))) unsigned int*)             \
                    (void*)((char*)lds + lofs),                               \
                16, 0, 0);                                                    \
        }                                                                     \
    }

    // prologue: tile 0 -> buffer 0
    ISSUE_TILE(gp0, 0)
    const float* __restrict__ gnext = gp0 + (size_t)CG * PLANE;

    for (int j = 0; j < TILES; ++j) {
        if (j + 1 < TILES) {
            ISSUE_TILE(gnext, ((j + 1) & 1))
            gnext += (size_t)CG * PLANE;
            // wait until only tile j+1's 7 loads remain -> tile j complete
            asm volatile("s_waitcnt vmcnt(7)" ::: "memory");
        } else {
            asm volatile("s_waitcnt vmcnt(0)" ::: "memory");
        }

        const int qb = (j & 1) * BUF_F + wv * CH_F;
        float m = -INFINITY;
        #pragma unroll
        for (int sy = 0; sy < SR; ++sy) {
            #pragma unroll
            for (int sx = 0; sx < SR; ++sx) {
                const int a0 = qb + r0a[sy][sx];
                const int a1 = qb + r1a[sy][sx];
                const float bil = w00[sy][sx] * lds[a0]
                                + w01[sy][sx] * lds[a0 + 1]
                                + w10[sy][sx] * lds[a1]
                                + w11[sy][sx] * lds[a1 + 1];
                m = fmaxf(m, bil);
            }
        }
        if (lane < CELLS)
            out[(size_t)n * PER_BOX + (size_t)(j * CG + wv) * CELLS + cell] = m;
    }
#undef ISSUE_TILE
}

extern "C" void kernel_launch(void* const* d_in, const int* in_sizes, int n_in,
                              void* d_out, int out_size, void* d_ws, size_t ws_size,
                              hipStream_t stream) {
    const float* feature   = (const float*)d_in[0];
    const float* boxes     = (const float*)d_in[1];
    const int*   batch_idx = (const int*)d_in[2];
    float*       out       = (float*)d_out;

    if (d_ws != nullptr && ws_size >= (size_t)Nc * sizeof(int)) {
        int* perm = (int*)d_ws;
        box_rank_kernel<<<Nc, 64, 0, stream>>>(boxes, batch_idx, perm);
        roi_align_max_kernel<true><<<Nc, 256, 0, stream>>>(
            feature, boxes, batch_idx, perm, out);
    } else {
        roi_align_max_kernel<false><<<Nc, 256, 0, stream>>>(
            feature, boxes, batch_idx, nullptr, out);
    }
}